// Round 16
// baseline (197.780 us; speedup 1.0000x reference)
//
#include <hip/hip_runtime.h>
#include <hip/hip_fp16.h>
#include <math.h>

#define ALPHA_C 0.5f
#define BETA_C  0.5f
#define NPART   256
#define NQUART  4

typedef _Float16 half8 __attribute__((ext_vector_type(8)));
typedef _Float16 half4v __attribute__((ext_vector_type(4)));
typedef _Float16 half2v __attribute__((ext_vector_type(2)));
typedef float f32x4 __attribute__((ext_vector_type(4)));

// XOR row-swizzle: spreads a column access across 8 LDS bank-groups.
// XORs byte-offset bits 4-6 only -> any access width <=16B that stays inside
// a 16B chunk sees a consistent involution.
__device__ __forceinline__ int swz(int row, int byteoff) {
    return byteoff ^ ((row & 7) << 4);
}

// 16B load tolerant of 4B alignment (z rows have stride 65 f32).
__device__ __forceinline__ f32x4 ldg16u(const float* p) {
    f32x4 v; __builtin_memcpy(&v, p, 16); return v;
}

// Exact degree histogram with NO global atomics (round-4 design).
__global__ __launch_bounds__(256) void k_hist(
        const int* __restrict__ eidx, unsigned int* __restrict__ scr,
        int N, int E, int Q, int Wd, int chunk) {
    const int s = blockIdx.x;
    const int role = blockIdx.y;
    const int dir = role & 1;
    const int q = role >> 1;
    extern __shared__ unsigned int lds[];          // Wd words
    for (int w = threadIdx.x; w < Wd; w += blockDim.x) lds[w] = 0;
    __syncthreads();
    const int base = q * Q;
    const int hi = min(N - base, Q);
    const int* __restrict__ arr = eidx + (size_t)dir * E;
    const int start = s * chunk;
    const int end = min(E, start + chunk);
    const int4* __restrict__ a4 = (const int4*)arr;
    const int v1 = end >> 2;
    for (int v = (start >> 2) + threadIdx.x; v < v1; v += blockDim.x) {
        int4 x = a4[v];
        int l;
        l = x.x - base; if ((unsigned)l < (unsigned)hi) atomicAdd(&lds[l >> 1], 1u << ((l & 1) * 16));
        l = x.y - base; if ((unsigned)l < (unsigned)hi) atomicAdd(&lds[l >> 1], 1u << ((l & 1) * 16));
        l = x.z - base; if ((unsigned)l < (unsigned)hi) atomicAdd(&lds[l >> 1], 1u << ((l & 1) * 16));
        l = x.w - base; if ((unsigned)l < (unsigned)hi) atomicAdd(&lds[l >> 1], 1u << ((l & 1) * 16));
    }
    for (int i = (v1 << 2) + threadIdx.x; i < end; i += blockDim.x) {
        int l = arr[i] - base;
        if ((unsigned)l < (unsigned)hi) atomicAdd(&lds[l >> 1], 1u << ((l & 1) * 16));
    }
    __syncthreads();
    unsigned int* __restrict__ dst = scr + ((size_t)role * gridDim.x + s) * Wd;
    for (int w = threadIdx.x; w < Wd; w += blockDim.x) dst[w] = lds[w];
}

// Fold slice histograms -> degrees + sum-of-squares partials.
// Also: streams z_self into P's middle third, block 0 builds f16 W^T.
__global__ __launch_bounds__(256) void k_fold(
        const unsigned int* __restrict__ scr,
        float* __restrict__ deg_out, float* __restrict__ deg_in,
        float* __restrict__ partials,
        const float* __restrict__ z_self, _Float16* __restrict__ P,
        const float* __restrict__ W_in, const float* __restrict__ W_out,
        _Float16* __restrict__ w16i, _Float16* __restrict__ w16o,
        int N, int Q, int Wd, int S) {
    float so = 0.f, si = 0.f;
    for (int n = blockIdx.x * blockDim.x + threadIdx.x; n < N;
         n += gridDim.x * blockDim.x) {
        const int q = n / Q, l = n - q * Q;
        const int w = l >> 1, sh = (l & 1) * 16;
        const unsigned int* __restrict__ p0 = scr + ((size_t)(q * 2 + 0) * S) * Wd + w;
        const unsigned int* __restrict__ p1 = scr + ((size_t)(q * 2 + 1) * S) * Wd + w;
        unsigned int a = 0, b = 0;
        for (int s = 0; s < S; ++s) {
            a += (p0[(size_t)s * Wd] >> sh) & 0xFFFFu;
            b += (p1[(size_t)s * Wd] >> sh) & 0xFFFFu;
        }
        float fa = (float)a, fb = (float)b;
        deg_out[n] = fa;
        deg_in[n] = fb;
        so = fmaf(fa, fa, so);
        si = fmaf(fb, fb, si);
    }
    // z_self -> P[:, 64:128) halfs (middle third), coalesced streaming.
    const int total = N * 16;
    for (int c = blockIdx.x * blockDim.x + threadIdx.x; c < total;
         c += gridDim.x * blockDim.x) {
        int row = c >> 4, c4 = c & 15;
        f32x4 v = *(const f32x4*)(z_self + (size_t)row * 64 + c4 * 4);
        half4v h = { (_Float16)v.x, (_Float16)v.y,
                     (_Float16)v.z, (_Float16)v.w };
        *(half4v*)(P + (size_t)row * 192 + 64 + c4 * 4) = h;
    }
    // block 0: f16 W^T build (tiny)
    if (blockIdx.x == 0) {
        for (int i = threadIdx.x; i < 4096; i += 256) {
            int k = i >> 6, n = i & 63;
            w16o[n * 64 + k] = (_Float16)W_out[k * 64 + n];
            w16i[n * 64 + k] = (_Float16)W_in [k * 64 + n];
        }
    }
#pragma unroll
    for (int off = 32; off; off >>= 1) {
        so += __shfl_xor(so, off);
        si += __shfl_xor(si, off);
    }
    __shared__ float sm[2][4];
    int lane = threadIdx.x & 63, w = threadIdx.x >> 6;
    if (lane == 0) { sm[0][w] = so; sm[1][w] = si; }
    __syncthreads();
    if (threadIdx.x == 0) {
        partials[blockIdx.x]         = sm[0][0] + sm[0][1] + sm[0][2] + sm[0][3];
        partials[NPART + blockIdx.x] = sm[1][0] + sm[1][1] + sm[1][2] + sm[1][3];
    }
}

// Norm finish only.
__global__ __launch_bounds__(256) void k_finish(
        const float* __restrict__ partials, float* __restrict__ inv_nrm) {
    int t = threadIdx.x;
    float so = partials[t], si = partials[NPART + t];
#pragma unroll
    for (int off = 32; off; off >>= 1) {
        so += __shfl_xor(so, off);
        si += __shfl_xor(si, off);
    }
    __shared__ float sm[2][4];
    int lane = t & 63, w = t >> 6;
    if (lane == 0) { sm[0][w] = so; sm[1][w] = si; }
    __syncthreads();
    if (t == 0) {
        float a = sm[0][0] + sm[0][1] + sm[0][2] + sm[0][3];
        float b = sm[1][0] + sm[1][1] + sm[1][2] + sm[1][3];
        inv_nrm[0] = (a > 0.f) ? rsqrtf(a) : 0.f;
        inv_nrm[1] = (b > 0.f) ? rsqrtf(b) : 0.f;
    }
}

// MFMA node precompute, LDS-staged. Phase-1 staging uses 16B f32x4 loads +
// 8B ds_write_b64 (4x fewer VMEM instructions than the 8B-load form; final
// LDS layout identical since swz only flips byte-bits 4-6).
// Fragment maps (verified rounds 5-15):
//   A[m][k]: m = lane&15, k = 32*s + 8*(lane>>4) + j
//   B[k][n]: n = lane&15, k = 32*s + 8*(lane>>4) + j  (w16 = W^T [n][k])
//   D[m][n]: n = lane&15, m = 4*(lane>>4) + reg
__global__ __launch_bounds__(256) void k_nodes(
        const float* __restrict__ z_in, const float* __restrict__ z_out,
        const _Float16* __restrict__ w16i, const _Float16* __restrict__ w16o,
        const float* __restrict__ b_in, const float* __restrict__ b_out,
        const float* __restrict__ deg_out, const float* __restrict__ deg_in,
        const float* __restrict__ inv_nrm,
        _Float16* __restrict__ P,
        float* __restrict__ s_src, float* __restrict__ s_dst, int N) {
    __shared__ _Float16 smem[16384];                 // 32 KB
    char* lzo = (char*)smem;                         // [64][64] f16, 8 KB
    char* lzi = (char*)smem + 8192;
    char* lwo = (char*)smem + 16384;                 // W^T [n=64][k=64] f16
    char* lwi = (char*)smem + 24576;
    char* lp  = (char*)smem;                         // [64][256B] results (aliases z)

    const int tid = threadIdx.x;
    const int lane = tid & 63;
    const int wid = tid >> 6;
    const int r = lane & 15, g = lane >> 4;
    const int base = blockIdx.x * 64;
    const int wrow = wid * 16;

    // ---- phase 1: stage z tiles (f32x4 -> half4, 8B ds writes) + W^T ----
#pragma unroll
    for (int it = 0; it < 4; ++it) {
        int flat = it * 256 + tid;                   // [0, 1024)
        int row = flat >> 4;                         // 0..63
        int c4 = flat & 15;                          // 16B chunk within row
        int grow = min(base + row, N - 1);
        f32x4 vo = ldg16u(z_out + (size_t)grow * 65 + c4 * 4);
        half4v ho = { (_Float16)vo.x, (_Float16)vo.y,
                      (_Float16)vo.z, (_Float16)vo.w };
        *(half4v*)(lzo + row * 128 + swz(row, c4 * 8)) = ho;
        f32x4 vi = ldg16u(z_in + (size_t)grow * 65 + c4 * 4);
        half4v hi = { (_Float16)vi.x, (_Float16)vi.y,
                      (_Float16)vi.z, (_Float16)vi.w };
        *(half4v*)(lzi + row * 128 + swz(row, c4 * 8)) = hi;
    }
#pragma unroll
    for (int it = 0; it < 2; ++it) {
        int flat = it * 256 + tid;                   // [0, 512) 16B chunks
        int n = flat >> 3;
        int c = flat & 7;
        *(half8*)(lwo + n * 128 + swz(n, c * 16)) = *(const half8*)(w16o + flat * 8);
        *(half8*)(lwi + n * 128 + swz(n, c * 16)) = *(const half8*)(w16i + flat * 8);
    }
    half8 bO[2], bI[2];
#pragma unroll
    for (int s = 0; s < 2; ++s)
#pragma unroll
        for (int j = 0; j < 8; ++j) {
            int k = 32 * s + 8 * g + j;
            bO[s][j] = (r == 0) ? (_Float16)b_out[k] : (_Float16)0.f;
            bI[s][j] = (r == 0) ? (_Float16)b_in [k] : (_Float16)0.f;
        }
    __syncthreads();

    // ---- phase 2: fragments from LDS + MFMA ----
    half8 AO[2], AI[2];
#pragma unroll
    for (int s = 0; s < 2; ++s) {
        int arow = wrow + r;
        int off = arow * 128 + swz(arow, s * 64 + g * 16);
        AO[s] = *(half8*)(lzo + off);
        AI[s] = *(half8*)(lzi + off);
    }
    f32x4 aO[4], aI[4], abO = (f32x4)0.f, abI = (f32x4)0.f;
#pragma unroll
    for (int t = 0; t < 4; ++t) { aO[t] = (f32x4)0.f; aI[t] = (f32x4)0.f; }
#pragma unroll
    for (int s = 0; s < 2; ++s) {
#pragma unroll
        for (int t = 0; t < 4; ++t) {
            int n = 16 * t + r;
            int off = n * 128 + swz(n, s * 64 + g * 16);
            half8 BO = *(half8*)(lwo + off);
            aO[t] = __builtin_amdgcn_mfma_f32_16x16x32_f16(AO[s], BO, aO[t], 0, 0, 0);
            half8 BI = *(half8*)(lwi + off);
            aI[t] = __builtin_amdgcn_mfma_f32_16x16x32_f16(AI[s], BI, aI[t], 0, 0, 0);
        }
        abO = __builtin_amdgcn_mfma_f32_16x16x32_f16(AO[s], bO[s], abO, 0, 0, 0);
        abI = __builtin_amdgcn_mfma_f32_16x16x32_f16(AI[s], bI[s], abI, 0, 0, 0);
    }
    __syncthreads();   // z tiles dead; lp aliases them

    // ---- phase 3: results into swizzled [64][256B] LDS tile ----
    // layout: bytes [0,128) = v_out, [128,256) = v_in
#pragma unroll
    for (int t = 0; t < 4; ++t)
#pragma unroll
        for (int rr = 0; rr < 4; ++rr) {
            int lrow = wrow + 4 * g + rr;
            int col2 = (16 * t + r) * 2;
            *(_Float16*)(lp + lrow * 256 + swz(lrow, col2)) = (_Float16)aO[t][rr];
            *(_Float16*)(lp + lrow * 256 + swz(lrow, 128 + col2)) = (_Float16)aI[t][rr];
        }
    if (r == 0) {
        const float i0 = inv_nrm[0], i1 = inv_nrm[1];
#pragma unroll
        for (int rr = 0; rr < 4; ++rr) {
            int m = base + wrow + 4 * g + rr;
            if (m < N) {
                s_src[m] = BETA_C * fmaf(deg_out[m], i0, z_out[(size_t)m * 65 + 64])
                         + ALPHA_C * abO[rr];
                s_dst[m] = BETA_C * fmaf(deg_in[m],  i1, z_in [(size_t)m * 65 + 64])
                         + ALPHA_C * abI[rr];
            }
        }
    }
    __syncthreads();

    // ---- phase 4: coalesced 16B/lane flush of the two outer thirds ----
#pragma unroll
    for (int it = 0; it < 4; ++it) {
        int flat = it * 256 + tid;                   // [0, 1024)
        int lrow = flat >> 4;
        int seg = flat & 15;                         // 0..7 v_out, 8..15 v_in
        int m = base + lrow;
        if (m < N) {
            half8 v = *(half8*)(lp + lrow * 256 + swz(lrow, seg * 16));
            int hoff = seg * 8 + ((seg >> 3) << 6);  // [0,64) or [128,192)
            *(half8*)(P + (size_t)m * 192 + hoff) = v;
        }
    }
}

// Per-edge: 16 lanes per TWO edges. src row = P[s][0:128), dst = P[d][64:192).
__global__ __launch_bounds__(256) void k_edges(
        const int* __restrict__ eidx, const _Float16* __restrict__ P,
        const float* __restrict__ s_src, const float* __restrict__ s_dst,
        float* __restrict__ out, int E) {
    const int sub = threadIdx.x & 15;
    const int grp = blockIdx.x * (blockDim.x >> 4) + (threadIdx.x >> 4);
    const int e0 = grp << 1;
    if (e0 >= E) return;
    const bool has1 = (e0 + 1) < E;
    int2 ss = *(const int2*)(eidx + e0);
    int2 dd = *(const int2*)(eidx + E + e0);
    const int s1 = has1 ? ss.y : ss.x, d1 = has1 ? dd.y : dd.x;
    const uint4 a0 = *(const uint4*)(P + (size_t)ss.x * 192 + sub * 8);
    const uint4 b0 = *(const uint4*)(P + (size_t)dd.x * 192 + 64 + sub * 8);
    const uint4 a1 = *(const uint4*)(P + (size_t)s1 * 192 + sub * 8);
    const uint4 b1 = *(const uint4*)(P + (size_t)d1 * 192 + 64 + sub * 8);
    float ssum = 0.f;
    if (sub < 2) {
        int s = sub ? s1 : ss.x;
        int d = sub ? d1 : dd.x;
        ssum = s_src[s] + s_dst[d];
    }
    float acc0 = 0.f, acc1 = 0.f;
    acc0 = __builtin_amdgcn_fdot2(__builtin_bit_cast(half2v, a0.x), __builtin_bit_cast(half2v, b0.x), acc0, false);
    acc0 = __builtin_amdgcn_fdot2(__builtin_bit_cast(half2v, a0.y), __builtin_bit_cast(half2v, b0.y), acc0, false);
    acc0 = __builtin_amdgcn_fdot2(__builtin_bit_cast(half2v, a0.z), __builtin_bit_cast(half2v, b0.z), acc0, false);
    acc0 = __builtin_amdgcn_fdot2(__builtin_bit_cast(half2v, a0.w), __builtin_bit_cast(half2v, b0.w), acc0, false);
    acc1 = __builtin_amdgcn_fdot2(__builtin_bit_cast(half2v, a1.x), __builtin_bit_cast(half2v, b1.x), acc1, false);
    acc1 = __builtin_amdgcn_fdot2(__builtin_bit_cast(half2v, a1.y), __builtin_bit_cast(half2v, b1.y), acc1, false);
    acc1 = __builtin_amdgcn_fdot2(__builtin_bit_cast(half2v, a1.z), __builtin_bit_cast(half2v, b1.z), acc1, false);
    acc1 = __builtin_amdgcn_fdot2(__builtin_bit_cast(half2v, a1.w), __builtin_bit_cast(half2v, b1.w), acc1, false);
#pragma unroll
    for (int off = 8; off; off >>= 1) {
        acc0 += __shfl_xor(acc0, off);
        acc1 += __shfl_xor(acc1, off);
    }
    if (sub < 2 && (sub == 0 || has1)) {
        float acc = sub ? acc1 : acc0;
        float v = fmaf(ALPHA_C, acc, ssum);
        out[e0 + sub] = 1.0f / (1.0f + __expf(-v));
    }
}

extern "C" void kernel_launch(void* const* d_in, const int* in_sizes, int n_in,
                              void* d_out, int out_size, void* d_ws, size_t ws_size,
                              hipStream_t stream) {
    const float* z_in   = (const float*)d_in[0];
    const float* z_out  = (const float*)d_in[1];
    const float* z_self = (const float*)d_in[2];
    const float* W_in   = (const float*)d_in[3];
    const float* b_in   = (const float*)d_in[4];
    const float* W_out  = (const float*)d_in[5];
    const float* b_out  = (const float*)d_in[6];
    const int*   eidx   = (const int*)d_in[7];

    const int N = in_sizes[2] / 64;   // z_self is [N, 64]
    const int E = in_sizes[7] / 2;    // edge_index is [2, E]

    // Histogram geometry: per-slice edge count < 65536 => u16-exact.
    const int Q = (N + NQUART - 1) / NQUART;
    const int Wd = (Q + 1) / 2;
    int S = (E + 49999) / 50000;
    if (S < 1) S = 1;
    int chunk = ((E + S - 1) / S + 3) & ~3;

    float* ws       = (float*)d_ws;
    float* deg_out  = ws;                             // N
    float* deg_in   = ws + (size_t)N;                 // N
    float* s_src    = ws + 2 * (size_t)N;             // N
    float* s_dst    = ws + 3 * (size_t)N;             // N
    _Float16* P     = (_Float16*)(ws + 4 * (size_t)N);        // N*192 fp16
    float* partials = (float*)(P + (size_t)N * 192);          // 2*NPART
    float* inv_nrm  = partials + 2 * NPART;                   // 2
    _Float16* w16o  = (_Float16*)(inv_nrm + 2 + 12);          // 4096 f16 (16B-aligned)
    _Float16* w16i  = w16o + 4096;                            // 4096 f16
    // scr DISJOINT from P (k_fold writes P while reading scr).
    unsigned int* scr = (unsigned int*)(w16i + 4096);         // 8*S*Wd words

    dim3 hgrid(S, 2 * NQUART);
    k_hist<<<hgrid, 256, (size_t)Wd * 4, stream>>>(eidx, scr, N, E, Q, Wd, chunk);
    k_fold<<<NPART, 256, 0, stream>>>(scr, deg_out, deg_in, partials,
                                      z_self, P, W_in, W_out, w16i, w16o,
                                      N, Q, Wd, S);
    k_finish<<<1, 256, 0, stream>>>(partials, inv_nrm);
    k_nodes<<<(N + 63) / 64, 256, 0, stream>>>(z_in, z_out, w16i, w16o,
                                               b_in, b_out, deg_out, deg_in,
                                               inv_nrm, P, s_src, s_dst, N);
    {
        int groups = (E + 1) / 2;
        int blocks = (groups + 15) / 16;
        k_edges<<<blocks, 256, 0, stream>>>(eidx, P, s_src, s_dst,
                                            (float*)d_out, E);
    }
}